// Round 1
// baseline (187.035 us; speedup 1.0000x reference)
//
#include <hip/hip_runtime.h>
#include <math.h>

// ---- problem constants ----
#define B_ 2
#define S_ 2048
#define DM_ 2048
#define H_ 16
#define HKV_ 4
#define D_ 128
#define NKV_ 512           // HKV*D
#define N_ 3072            // DM + 2*NKV
#define M_ 4096            // B*S
#define CHK_ 32            // chunk length
#define NC_ 64             // S/CHK
#define SCALE_ 0.08838834764831845f
#define CLAMP_ 0.95f

typedef unsigned short u16;
typedef u16 ushortx8 __attribute__((ext_vector_type(8)));
typedef __bf16 bf16x8 __attribute__((ext_vector_type(8)));
typedef float f32x4 __attribute__((ext_vector_type(4)));

#define ASYNC16(gsrc, ldst) \
  __builtin_amdgcn_global_load_lds((const __attribute__((address_space(1))) void*)(gsrc), \
                                   (__attribute__((address_space(3))) void*)(ldst), 16, 0, 0)

__device__ __forceinline__ u16 f2b(float x){
  unsigned u = __float_as_uint(x);
  return (u16)((u + 0x7FFFu + ((u >> 16) & 1u)) >> 16);
}
__device__ __forceinline__ float b2f(u16 h){
  return __uint_as_float(((unsigned)h) << 16);
}
__device__ __forceinline__ bf16x8 ld8(const u16* p){
  return __builtin_bit_cast(bf16x8, *(const ushortx8*)p);
}
__device__ __forceinline__ f32x4 mfma16(bf16x8 a, bf16x8 b, f32x4 c){
  return __builtin_amdgcn_mfma_f32_16x16x32_bf16(a, b, c, 0, 0, 0);
}

// ---------------- f32 -> bf16 convert (8 elems/thread) ----------------
__global__ void k_cvt(const float* __restrict__ in, u16* __restrict__ out, int n8){
  int i = blockIdx.x * blockDim.x + threadIdx.x;
  if (i >= n8) return;
  const float4* p = (const float4*)in + (size_t)i * 2;
  float4 a = p[0], c = p[1];
  ushortx8 o;
  o[0]=f2b(a.x); o[1]=f2b(a.y); o[2]=f2b(a.z); o[3]=f2b(a.w);
  o[4]=f2b(c.x); o[5]=f2b(c.y); o[6]=f2b(c.z); o[7]=f2b(c.w);
  *(ushortx8*)(out + (size_t)i * 8) = o;
}

// ---------------- fused QKV GEMM: out = hs @ Wc^T, epilogue per region ----------------
// A [4096][2048] bf16, W [3072][2048] bf16 (both K-major). 128x128 tile, BK=32, 4 waves.
__launch_bounds__(256, 2)
__global__ void k_gemm(const u16* __restrict__ A, const u16* __restrict__ W,
                       const float* __restrict__ bq, const float* __restrict__ bk,
                       const float* __restrict__ bv,
                       u16* __restrict__ qp, u16* __restrict__ kp,
                       float* __restrict__ gG, u16* __restrict__ vT){
  __shared__ u16 Al[128 * 32];
  __shared__ u16 Bl[128 * 32];
  const int tid = threadIdx.x;
  const int wid = tid >> 6, lane = tid & 63;
  const int m0 = blockIdx.y * 128, n0 = blockIdx.x * 128;
  const int wr = (wid >> 1) * 64, wc = (wid & 1) * 64;
  const int lr = lane & 15, lk = (lane >> 4) * 8;
  f32x4 acc[4][4] = {};
  for (int kt = 0; kt < 64; ++kt){
    const int k0 = kt * 32;
    #pragma unroll
    for (int s = 0; s < 2; ++s){
      const int fo = (wid * 2 + s) * 512;   // wave-uniform LDS base (elems)
      const int el = fo + lane * 8;
      const int row = el >> 5, kk = el & 31;
      ASYNC16(A + (size_t)(m0 + row) * DM_ + k0 + kk, Al + fo);
      ASYNC16(W + (size_t)(n0 + row) * DM_ + k0 + kk, Bl + fo);
    }
    __syncthreads();
    bf16x8 af[4], bfr[4];
    #pragma unroll
    for (int i = 0; i < 4; ++i) af[i]  = ld8(&Al[(wr + i*16 + lr)*32 + lk]);
    #pragma unroll
    for (int j = 0; j < 4; ++j) bfr[j] = ld8(&Bl[(wc + j*16 + lr)*32 + lk]);
    #pragma unroll
    for (int i = 0; i < 4; ++i)
      #pragma unroll
      for (int j = 0; j < 4; ++j)
        acc[i][j] = mfma16(af[i], bfr[j], acc[i][j]);
    __syncthreads();
  }
  const int lg4 = lane >> 4;
  const int tn = blockIdx.x;
  if (tn < 16){                       // ---- q region: relu * scale ----
    #pragma unroll
    for (int i = 0; i < 4; ++i){
      const int rb = m0 + wr + i*16 + lg4*4;
      #pragma unroll
      for (int j = 0; j < 4; ++j){
        const int col = n0 + wc + j*16 + lr;
        const float bb = bq[col];
        #pragma unroll
        for (int r = 0; r < 4; ++r){
          float q = fmaxf(acc[i][j][r] + bb, 0.f) * SCALE_;
          qp[(size_t)(rb + r) * DM_ + col] = f2b(q);
        }
      }
    }
  } else if (tn < 20){                // ---- k region: kf = min(sigmoid,0.95), g = log1p(-kf) ----
    #pragma unroll
    for (int i = 0; i < 4; ++i){
      const int rb = m0 + wr + i*16 + lg4*4;
      #pragma unroll
      for (int j = 0; j < 4; ++j){
        const int cc = n0 - DM_ + wc + j*16 + lr;
        const float bb = bk[cc];
        #pragma unroll
        for (int r = 0; r < 4; ++r){
          float x = acc[i][j][r] + bb;
          float kf = fminf(1.f / (1.f + __expf(-x)), CLAMP_);
          kp[(size_t)(rb + r) * NKV_ + cc] = f2b(kf);
          gG[(size_t)(rb + r) * NKV_ + cc] = log1pf(-kf);
        }
      }
    }
  } else {                            // ---- v region: write transposed vT[b][kv][e][s] ----
    #pragma unroll
    for (int i = 0; i < 4; ++i){
      const int rb = m0 + wr + i*16 + lg4*4;
      const int bb_ = rb >> 11;
      const int srow = rb & 2047;
      #pragma unroll
      for (int j = 0; j < 4; ++j){
        const int cc = n0 - DM_ - NKV_ + wc + j*16 + lr;
        const float bias = bv[cc];
        const int kv = cc >> 7, e = cc & 127;
        ushort4 pk;
        pk.x = f2b(acc[i][j][0] + bias);
        pk.y = f2b(acc[i][j][1] + bias);
        pk.z = f2b(acc[i][j][2] + bias);
        pk.w = f2b(acc[i][j][3] + bias);
        *(ushort4*)(vT + (((size_t)(bb_ * HKV_ + kv) * D_ + e) * S_ + srow)) = pk;
      }
    }
  }
}

// ---------------- per-chunk inclusive cumsum of g (in place) + chunk decay ----------------
__global__ void k_cumsum(float* __restrict__ g, float* __restrict__ dec){
  const int c = blockIdx.x, b = blockIdx.y;
  const int col = threadIdx.x;        // 512 = kv*128+d
  const size_t base = ((size_t)b * S_ + (size_t)c * CHK_) * NKV_ + col;
  float v[CHK_];
  #pragma unroll
  for (int t = 0; t < CHK_; ++t) v[t] = g[base + (size_t)t * NKV_];
  float acc = 0.f;
  #pragma unroll
  for (int t = 0; t < CHK_; ++t){ acc += v[t]; v[t] = acc; }
  #pragma unroll
  for (int t = 0; t < CHK_; ++t) g[base + (size_t)t * NKV_] = v[t];
  const int kv = col >> 7, d = col & 127;
  dec[(((size_t)b * HKV_ + kv) * NC_ + c) * D_ + d] = __expf(acc);
}

// ---------------- per-chunk state contribution:  SSt[c][e][d] = sum_t v[t][e]*kf[t][d]*exp(G31-G_t) ----------------
__launch_bounds__(256, 2)
__global__ void k_dstate(const u16* __restrict__ kp, const float* __restrict__ G,
                         const u16* __restrict__ vT, u16* __restrict__ SSt){
  __shared__ float kex[CHK_][D_];     // 16 KB
  __shared__ float vl[D_][CHK_ + 1];  // padded: bank-conflict-free per-lane reads
  const int c = blockIdx.x, kv = blockIdx.y, b = blockIdx.z;
  const int tid = threadIdx.x;
  const int s0 = c * CHK_;
  const size_t gbase = ((size_t)b * S_ + s0) * NKV_ + kv * D_;
  for (int idx = tid; idx < CHK_ * D_; idx += 256){
    const int t = idx >> 7, d = idx & 127;
    const float Gt  = G[gbase + (size_t)t  * NKV_ + d];
    const float G31 = G[gbase + (size_t)31 * NKV_ + d];
    const float kf = b2f(kp[gbase + (size_t)t * NKV_ + d]);
    kex[t][d] = kf * __expf(G31 - Gt);
  }
  const size_t vbase = ((size_t)(b * HKV_ + kv) * D_) * S_ + s0;
  for (int idx = tid; idx < 512; idx += 256){
    const int e = idx >> 2, t8 = (idx & 3) * 8;
    ushortx8 vv = *(const ushortx8*)(vT + vbase + (size_t)e * S_ + t8);
    #pragma unroll
    for (int u = 0; u < 8; ++u) vl[e][t8 + u] = b2f(vv[u]);
  }
  __syncthreads();
  const int w = tid >> 6, lane = tid & 63;
  const int e = (w & 1) * 64 + lane;
  const int d0 = (w >> 1) * 64;
  float acc[64];
  #pragma unroll
  for (int i = 0; i < 64; ++i) acc[i] = 0.f;
  for (int t = 0; t < CHK_; ++t){
    const float vv = vl[e][t];
    const float4* kr = (const float4*)(&kex[t][d0]);
    #pragma unroll
    for (int i4 = 0; i4 < 16; ++i4){
      float4 kk = kr[i4];
      acc[i4*4+0] = fmaf(vv, kk.x, acc[i4*4+0]);
      acc[i4*4+1] = fmaf(vv, kk.y, acc[i4*4+1]);
      acc[i4*4+2] = fmaf(vv, kk.z, acc[i4*4+2]);
      acc[i4*4+3] = fmaf(vv, kk.w, acc[i4*4+3]);
    }
  }
  const size_t ob = (((size_t)(b * HKV_ + kv) * NC_ + c) * D_ + e) * D_ + d0;
  #pragma unroll
  for (int i8 = 0; i8 < 8; ++i8){
    ushortx8 o;
    #pragma unroll
    for (int u = 0; u < 8; ++u) o[u] = f2b(acc[i8*8 + u]);
    *(ushortx8*)(SSt + ob + i8*8) = o;
  }
}

// ---------------- elementwise scan over chunks (in place: dS -> S_start) ----------------
__global__ void k_scan(u16* __restrict__ SSt, const float* __restrict__ dec){
  const int eg = blockIdx.x, kv = blockIdx.y, b = blockIdx.z;
  const int tid = threadIdx.x;
  const int e = eg * 8 + (tid >> 5);
  const int d4 = (tid & 31) * 4;
  const size_t base  = ((size_t)(b * HKV_ + kv) * NC_) * D_ * D_ + (size_t)e * D_ + d4;
  const size_t dbase = ((size_t)(b * HKV_ + kv) * NC_) * D_ + d4;
  float s0 = 0.f, s1 = 0.f, s2 = 0.f, s3 = 0.f;
  for (int c = 0; c < NC_; ++c){
    const size_t off = base + (size_t)c * (D_ * D_);
    ushort4 dv = *(ushort4*)(SSt + off);
    float4 dc = *(const float4*)(dec + dbase + (size_t)c * D_);
    ushort4 wr;
    wr.x = f2b(s0); wr.y = f2b(s1); wr.z = f2b(s2); wr.w = f2b(s3);
    *(ushort4*)(SSt + off) = wr;
    s0 = s0 * dc.x + b2f(dv.x);
    s1 = s1 * dc.y + b2f(dv.y);
    s2 = s2 * dc.z + b2f(dv.z);
    s3 = s3 * dc.w + b2f(dv.w);
  }
}

// ---------------- output: O = (q e^G) @ S_start + masked-decayed QK^T @ V ----------------
__launch_bounds__(256, 2)
__global__ void k_out(const u16* __restrict__ qp, const u16* __restrict__ kp,
                      const float* __restrict__ G, const u16* __restrict__ vT,
                      const u16* __restrict__ SSt, float* __restrict__ out){
  __shared__ u16 QeF[32 * 128];   // q * e^{G_t}
  __shared__ u16 Qe1[16 * 128];   // rows 16..31: q * e^{G_t - G15}
  __shared__ u16 Ke0[16 * 128];   // kf * e^{-G_tau}, tau<16
  __shared__ u16 Ke1[32 * 128];   // kf * e^{G15 - G_tau}
  __shared__ u16 Sb[128 * 128];   // S_start^T [e][d]
  __shared__ u16 Am[32 * 32];     // intra score matrix (masked)
  __shared__ float G15[128];
  const int c = blockIdx.x, h = blockIdx.y, b = blockIdx.z;
  const int kv = h >> 2;
  const int tid = threadIdx.x, wid = tid >> 6, lane = tid & 63;
  const int s0 = c * CHK_;
  const int lr = lane & 15, lk = (lane >> 4) * 8;
  const size_t gb = ((size_t)b * S_ + s0) * NKV_ + kv * D_;
  const size_t qb = ((size_t)b * S_ + s0) * DM_ + h * D_;
  const size_t vb = ((size_t)(b * HKV_ + kv) * D_) * S_ + s0;
  if (tid < 128) G15[tid] = G[gb + (size_t)15 * NKV_ + tid];
  __syncthreads();
  for (int idx = tid; idx < 32 * 128; idx += 256){
    const int t = idx >> 7, d = idx & 127;
    const float Gt = G[gb + (size_t)t * NKV_ + d];
    const float q = b2f(qp[qb + (size_t)t * DM_ + d]);
    QeF[idx] = f2b(q * __expf(Gt));
    if (t >= 16) Qe1[(t - 16) * 128 + d] = f2b(q * __expf(Gt - G15[d]));
    const float kf = b2f(kp[gb + (size_t)t * NKV_ + d]);
    if (t < 16) Ke0[idx] = f2b(kf * __expf(-Gt));
    Ke1[idx] = f2b(kf * __expf(G15[d] - Gt));
  }
  {   // S_start^T -> LDS, linear async copy (32 KB)
    const u16* src = SSt + (((size_t)(b * HKV_ + kv) * NC_ + c) * (D_ * D_));
    #pragma unroll
    for (int is = 0; is < 8; ++is){
      const int fo = is * 2048 + wid * 512;
      ASYNC16(src + fo + lane * 8, ((u16*)Sb) + fo);
    }
  }
  __syncthreads();
  // ---- intra score blocks (sub-chunk 16 factorization) ----
  if (wid == 1){
    for (int i = lane; i < 256; i += 64) Am[(i >> 4) * 32 + 16 + (i & 15)] = 0;
  } else {
    const u16* aQ = (wid == 0) ? QeF : Qe1;
    const u16* aK = (wid == 0) ? Ke0 : Ke1;
    const int tauBase = (wid == 3) ? 16 : 0;
    f32x4 a4 = {};
    #pragma unroll
    for (int kd = 0; kd < 4; ++kd){
      bf16x8 fa = ld8(&aQ[lr * 128 + kd * 32 + lk]);
      bf16x8 fb = ld8(&aK[(tauBase + lr) * 128 + kd * 32 + lk]);
      a4 = mfma16(fa, fb, a4);
    }
    const int rowb = (wid == 0) ? 0 : 16;
    const int colb = (wid == 3) ? 16 : 0;
    const bool diag = (wid == 0) || (wid == 3);
    #pragma unroll
    for (int r = 0; r < 4; ++r){
      const int rr = (lane >> 4) * 4 + r;
      float v = a4[r];
      if (diag && lr > rr) v = 0.f;     // causal mask tau <= t
      Am[(rowb + rr) * 32 + colb + lr] = f2b(v);
    }
  }
  __syncthreads();
  // ---- O = QeF @ Sb  +  Am @ V ----
  f32x4 o4[2][2] = {};
  const int ew = wid * 32;
  #pragma unroll
  for (int kd = 0; kd < 4; ++kd){
    bf16x8 fa0 = ld8(&QeF[(0  + lr) * 128 + kd * 32 + lk]);
    bf16x8 fa1 = ld8(&QeF[(16 + lr) * 128 + kd * 32 + lk]);
    bf16x8 fb0 = ld8(&Sb[(ew + lr) * 128 + kd * 32 + lk]);
    bf16x8 fb1 = ld8(&Sb[(ew + 16 + lr) * 128 + kd * 32 + lk]);
    o4[0][0] = mfma16(fa0, fb0, o4[0][0]);
    o4[0][1] = mfma16(fa0, fb1, o4[0][1]);
    o4[1][0] = mfma16(fa1, fb0, o4[1][0]);
    o4[1][1] = mfma16(fa1, fb1, o4[1][1]);
  }
  {
    bf16x8 fa0 = ld8(&Am[lr * 32 + lk]);
    bf16x8 fa1 = ld8(&Am[(16 + lr) * 32 + lk]);
    const u16* vr0 = vT + vb + (size_t)(ew + lr) * S_;
    const u16* vr1 = vT + vb + (size_t)(ew + 16 + lr) * S_;
    bf16x8 fb0 = ld8(vr0 + lk);          // V fragments straight from global (vT is e-major)
    bf16x8 fb1 = ld8(vr1 + lk);
    o4[0][0] = mfma16(fa0, fb0, o4[0][0]);
    o4[0][1] = mfma16(fa0, fb1, o4[0][1]);
    o4[1][0] = mfma16(fa1, fb0, o4[1][0]);
    o4[1][1] = mfma16(fa1, fb1, o4[1][1]);
  }
  #pragma unroll
  for (int i2 = 0; i2 < 2; ++i2)
    #pragma unroll
    for (int j2 = 0; j2 < 2; ++j2)
      #pragma unroll
      for (int r = 0; r < 4; ++r){
        const int t = i2 * 16 + (lane >> 4) * 4 + r;
        const int e = ew + j2 * 16 + lr;
        out[((size_t)b * S_ + s0 + t) * DM_ + h * D_ + e] = o4[i2][j2][r];
      }
}

// ---------------- host launch ----------------
extern "C" void kernel_launch(void* const* d_in, const int* in_sizes, int n_in,
                              void* d_out, int out_size, void* d_ws, size_t ws_size,
                              hipStream_t stream){
  const float* hs = (const float*)d_in[0];
  const float* Wq = (const float*)d_in[1];
  const float* bq = (const float*)d_in[2];
  const float* Wk = (const float*)d_in[3];
  const float* bk = (const float*)d_in[4];
  const float* Wv = (const float*)d_in[5];
  const float* bv = (const float*)d_in[6];
  char* ws = (char*)d_ws;
  u16*   hsb = (u16*)(ws);                                  // 16,777,216 B
  u16*   wcb = (u16*)(ws + 16777216);                       // 12,582,912 B
  u16*   qp  = (u16*)(ws + 29360128);                       // 16,777,216 B
  u16*   kp  = (u16*)(ws + 46137344);                       //  4,194,304 B
  float* gG  = (float*)(ws + 50331648);                     //  8,388,608 B
  u16*   vT  = (u16*)(ws + 58720256);                       //  4,194,304 B
  float* dec = (float*)(ws + 62914560);                     //    262,144 B
  u16*   SSt = (u16*)(ws + 63176704);                       // 16,777,216 B -> total ~76.3 MB
  float* out = (float*)d_out;

  k_cvt<<<dim3(4096), 256, 0, stream>>>(hs, hsb, 1048576);
  k_cvt<<<dim3(2048), 256, 0, stream>>>(Wq, wcb, 524288);
  k_cvt<<<dim3(512),  256, 0, stream>>>(Wk, wcb + (size_t)2048 * 2048, 131072);
  k_cvt<<<dim3(512),  256, 0, stream>>>(Wv, wcb + (size_t)2560 * 2048, 131072);
  k_gemm<<<dim3(24, 32), 256, 0, stream>>>(hsb, wcb, bq, bk, bv, qp, kp, gG, vT);
  k_cumsum<<<dim3(NC_, B_), 512, 0, stream>>>(gG, dec);
  k_dstate<<<dim3(NC_, HKV_, B_), 256, 0, stream>>>(kp, gG, vT, SSt);
  k_scan<<<dim3(16, HKV_, B_), 256, 0, stream>>>(SSt, dec);
  k_out<<<dim3(NC_, H_, B_), 256, 0, stream>>>(qp, kp, gG, vT, SSt, out);
}